// Round 1
// baseline (217.642 us; speedup 1.0000x reference)
//
#include <hip/hip_runtime.h>

// ---------------------------------------------------------------------------
// Fused attention block, bf16 MFMA pipeline.
// ws layout (needs 40 MB):
//   [0,8M)    xb   : x as bf16 [4096][1024]   (reused as Ob after gemm_qkv)
//   [8M,14M)  WqT  : W_qkv^T bf16 [3072][1024]
//   [14M,16M) WpT  : W_proj^T bf16 [1024][1024]
//   [16M,24M) Qb   : [32][2048][64] bf16
//   [24M,32M) Kb   : [32][2048][64] bf16
//   [32M,40M) Vt   : [32][64][2048] bf16 (V transposed per head)
// ---------------------------------------------------------------------------

typedef __bf16 bf16_t;
typedef __bf16 bf16x2 __attribute__((ext_vector_type(2)));
typedef __bf16 bf16x8 __attribute__((ext_vector_type(8)));
typedef float  f32x4  __attribute__((ext_vector_type(4)));

#define NTOK 2048
#define DIM  1024
#define NH   16
#define HD   64
#define SCL2 0.18033688011112042f   // (1/8) * log2(e)

#define MFMA16(a, b, c) __builtin_amdgcn_mfma_f32_16x16x32_bf16((a), (b), (c), 0, 0, 0)

__device__ __forceinline__ void gload_lds16(const void* g, void* l) {
  __builtin_amdgcn_global_load_lds((const __attribute__((address_space(1))) void*)g,
                                   (__attribute__((address_space(3))) void*)l, 16, 0, 0);
}

// ---------------- fp32 -> bf16 convert (8 elems/thread) ----------------
__global__ __launch_bounds__(256) void k_cvt(const float* __restrict__ in,
                                             bf16_t* __restrict__ out) {
  int i = (blockIdx.x * 256 + threadIdx.x) * 8;
  float4 a = *(const float4*)(in + i);
  float4 b = *(const float4*)(in + i + 4);
  bf16x8 v;
  v[0] = (bf16_t)a.x; v[1] = (bf16_t)a.y; v[2] = (bf16_t)a.z; v[3] = (bf16_t)a.w;
  v[4] = (bf16_t)b.x; v[5] = (bf16_t)b.y; v[6] = (bf16_t)b.z; v[7] = (bf16_t)b.w;
  *(bf16x8*)(out + i) = v;
}

// ---------------- fp32 [rows][cols] -> bf16 [cols][rows] ----------------
__global__ __launch_bounds__(256) void k_transpose_cvt(const float* __restrict__ W,
                                                       bf16_t* __restrict__ WT,
                                                       int rows, int cols) {
  __shared__ float tile[32][33];
  int j0 = blockIdx.x * 32, i0 = blockIdx.y * 32;
  int c = threadIdx.x & 31, r0 = threadIdx.x >> 5;
#pragma unroll
  for (int it = 0; it < 4; ++it) {
    int r = r0 + it * 8;
    tile[r][c] = W[(long)(i0 + r) * cols + j0 + c];
  }
  __syncthreads();
#pragma unroll
  for (int it = 0; it < 4; ++it) {
    int r = r0 + it * 8;
    WT[(long)(j0 + r) * rows + i0 + c] = (bf16_t)tile[c][r];
  }
}

// ---------------- m97-style GEMM core: C = A * B^T ----------------
// A: [M][K] bf16 row-major, B: [N][K] bf16 row-major. 128x128 tile, BK=32,
// 256 threads = 4 waves (2x2), each wave 64x64 = 4x4 frags of 16x16x32.
__device__ __forceinline__ void gemm_core(const bf16_t* __restrict__ A,
                                          const bf16_t* __restrict__ B,
                                          int K, int bm, int bn,
                                          bf16_t* As, bf16_t* Bs, f32x4 acc[4][4]) {
  const int t = threadIdx.x;
  const int lane = t & 63;
  const int w = t >> 6;
  const int wr = (w >> 1) * 64, wc = (w & 1) * 64;
  const int l15 = lane & 15, g = lane >> 4;
  const int srow = t >> 2, scol = (t & 3) * 8;  // staging: LDS byte off = 16*t
  const f32x4 vzero = {0.f, 0.f, 0.f, 0.f};
#pragma unroll
  for (int m = 0; m < 4; ++m)
#pragma unroll
    for (int n = 0; n < 4; ++n) acc[m][n] = vzero;

  const bf16_t* ga = A + (long)(bm + srow) * K + scol;
  const bf16_t* gb = B + (long)(bn + srow) * K + scol;
  bf16_t* lA = As + srow * 32 + scol;
  bf16_t* lB = Bs + srow * 32 + scol;
  const long rstep = 64l * K;

  for (int k0 = 0; k0 < K; k0 += 32) {
    gload_lds16(ga + k0,         lA);
    gload_lds16(ga + rstep + k0, lA + 64 * 32);
    gload_lds16(gb + k0,         lB);
    gload_lds16(gb + rstep + k0, lB + 64 * 32);
    __syncthreads();  // drains vmcnt: LDS tiles valid
    bf16x8 af[4], bfv[4];
#pragma unroll
    for (int m = 0; m < 4; ++m)
      af[m] = *(const bf16x8*)(As + (wr + m * 16 + l15) * 32 + g * 8);
#pragma unroll
    for (int n = 0; n < 4; ++n)
      bfv[n] = *(const bf16x8*)(Bs + (wc + n * 16 + l15) * 32 + g * 8);
#pragma unroll
    for (int m = 0; m < 4; ++m)
#pragma unroll
      for (int n = 0; n < 4; ++n)
        acc[m][n] = MFMA16(af[m], bfv[n], acc[m][n]);
    __syncthreads();  // all reads done before next stage overwrites
  }
}

// ---------------- GEMM1: qkv = x @ W_qkv + b, scatter to Q/K/Vt ----------------
__global__ __launch_bounds__(256) void k_gemm_qkv(const bf16_t* __restrict__ xb,
                                                  const bf16_t* __restrict__ WqT,
                                                  const float* __restrict__ bq,
                                                  bf16_t* __restrict__ Qb,
                                                  bf16_t* __restrict__ Kb,
                                                  bf16_t* __restrict__ Vt) {
  __shared__ alignas(16) bf16_t As[128 * 32];
  __shared__ alignas(16) bf16_t Bs[128 * 32];
  f32x4 acc[4][4];
  const int bm = blockIdx.y * 128, bn = blockIdx.x * 128;
  gemm_core(xb, WqT, DIM, bm, bn, As, Bs, acc);

  const int lane = threadIdx.x & 63, w = threadIdx.x >> 6;
  const int wr = (w >> 1) * 64, wc = (w & 1) * 64;
  const int l15 = lane & 15, g = lane >> 4;
#pragma unroll
  for (int n = 0; n < 4; ++n) {
    int col = bn + wc + n * 16 + l15;           // 0..3071
    float bias = bq[col];
    int t3 = col >> 10, rem = col & 1023;
    int h = rem >> 6, d = rem & 63;
#pragma unroll
    for (int m = 0; m < 4; ++m) {
      int rowb = bm + wr + m * 16 + g * 4;
#pragma unroll
      for (int r = 0; r < 4; ++r) {
        int row = rowb + r;                     // token index 0..4095
        int b = row >> 11, tok = row & 2047;
        int bh = b * NH + h;
        bf16_t v = (bf16_t)(acc[m][n][r] + bias);
        if (t3 == 0)      Qb[bh * (NTOK * HD) + tok * HD + d] = v;
        else if (t3 == 1) Kb[bh * (NTOK * HD) + tok * HD + d] = v;
        else              Vt[bh * (NTOK * HD) + d * NTOK + tok] = v;
      }
    }
  }
}

// ---------------- flash attention (swapped QK^T, online softmax) ----------------
// grid = B*H*16 blocks; block = 4 waves; each wave owns 32 q-rows, streams
// k-tiles of 64. Computes S^T = mfma(K,Q) so a lane holds a full score row
// for q = lane&15 (+16*qf); P repacked via wave-private LDS into B-frags;
// O^T accumulated via mfma(Vt, P).
__global__ __launch_bounds__(256) void k_attn(const bf16_t* __restrict__ Qb,
                                              const bf16_t* __restrict__ Kb,
                                              const bf16_t* __restrict__ Vt,
                                              bf16_t* __restrict__ Ob) {
  __shared__ alignas(16) bf16_t P[4][32][72];   // per-wave, padded (+8) rows
  const int bid = blockIdx.x;
  const int qt = bid & 15, bh = bid >> 4;
  const int b = bh >> 4, h = bh & 15;
  const int w = threadIdx.x >> 6, lane = threadIdx.x & 63;
  const int l15 = lane & 15, g = lane >> 4;
  const bf16_t* Qp = Qb + bh * (NTOK * HD);
  const bf16_t* Kp = Kb + bh * (NTOK * HD);
  const bf16_t* Vp = Vt + bh * (NTOK * HD);
  const int q0 = qt * 128 + w * 32;

  bf16x8 qfr[2][2];
#pragma unroll
  for (int qf = 0; qf < 2; ++qf)
#pragma unroll
    for (int kk = 0; kk < 2; ++kk)
      qfr[qf][kk] = *(const bf16x8*)(Qp + (q0 + qf * 16 + l15) * HD + kk * 32 + g * 8);

  const f32x4 vzero = {0.f, 0.f, 0.f, 0.f};
  f32x4 o[4][2];
#pragma unroll
  for (int df = 0; df < 4; ++df) { o[df][0] = vzero; o[df][1] = vzero; }
  float m2[2]   = {-3.0e38f, -3.0e38f};
  float lsum[2] = {0.f, 0.f};

  for (int kt = 0; kt < NTOK; kt += 64) {
    // ---- S^T = K * Q^T  (rows = k-local, cols = q-local) ----
    f32x4 s[4][2];
#pragma unroll
    for (int kf = 0; kf < 4; ++kf) { s[kf][0] = vzero; s[kf][1] = vzero; }
#pragma unroll
    for (int kf = 0; kf < 4; ++kf) {
      const bf16_t* kr = Kp + (kt + kf * 16 + l15) * HD + g * 8;
      bf16x8 ka0 = *(const bf16x8*)kr;
      bf16x8 ka1 = *(const bf16x8*)(kr + 32);
#pragma unroll
      for (int qf = 0; qf < 2; ++qf) {
        s[kf][qf] = MFMA16(ka0, qfr[qf][0], s[kf][qf]);
        s[kf][qf] = MFMA16(ka1, qfr[qf][1], s[kf][qf]);
      }
    }
    // ---- online softmax per q-row (lane-local + 2 shuffles over g) ----
#pragma unroll
    for (int qf = 0; qf < 2; ++qf) {
      float mx = -3.0e38f;
#pragma unroll
      for (int kf = 0; kf < 4; ++kf)
#pragma unroll
        for (int r = 0; r < 4; ++r) mx = fmaxf(mx, s[kf][qf][r]);
      mx = fmaxf(mx, __shfl_xor(mx, 16));
      mx = fmaxf(mx, __shfl_xor(mx, 32));
      mx *= SCL2;
      float mn = fmaxf(m2[qf], mx);
      float corr = exp2f(m2[qf] - mn);
      m2[qf] = mn;
      float rs = 0.f;
#pragma unroll
      for (int kf = 0; kf < 4; ++kf) {
        float p0 = exp2f(s[kf][qf][0] * SCL2 - mn);
        float p1 = exp2f(s[kf][qf][1] * SCL2 - mn);
        float p2 = exp2f(s[kf][qf][2] * SCL2 - mn);
        float p3 = exp2f(s[kf][qf][3] * SCL2 - mn);
        rs += (p0 + p1) + (p2 + p3);
        bf16x2 w0; w0[0] = (bf16_t)p0; w0[1] = (bf16_t)p1;
        bf16x2 w1; w1[0] = (bf16_t)p2; w1[1] = (bf16_t)p3;
        *(bf16x2*)&P[w][qf * 16 + l15][kf * 16 + g * 4]     = w0;
        *(bf16x2*)&P[w][qf * 16 + l15][kf * 16 + g * 4 + 2] = w1;
      }
      rs += __shfl_xor(rs, 16);
      rs += __shfl_xor(rs, 32);
      lsum[qf] = lsum[qf] * corr + rs;
#pragma unroll
      for (int df = 0; df < 4; ++df) o[df][qf] *= corr;
    }
    // ---- O^T += Vt * P^T ----
#pragma unroll
    for (int kb = 0; kb < 2; ++kb) {
      bf16x8 pf0 = *(const bf16x8*)&P[w][l15][kb * 32 + g * 8];
      bf16x8 pf1 = *(const bf16x8*)&P[w][16 + l15][kb * 32 + g * 8];
#pragma unroll
      for (int df = 0; df < 4; ++df) {
        bf16x8 va = *(const bf16x8*)(Vp + (df * 16 + l15) * NTOK + kt + kb * 32 + g * 8);
        o[df][0] = MFMA16(va, pf0, o[df][0]);
        o[df][1] = MFMA16(va, pf1, o[df][1]);
      }
    }
  }
  // ---- normalize + write O[b][tok][h*64+d] (bf16, feeds proj GEMM) ----
#pragma unroll
  for (int qf = 0; qf < 2; ++qf) {
    float inv = 1.0f / lsum[qf];
    int tok = q0 + qf * 16 + l15;
    bf16_t* op = Ob + (long)(b * NTOK + tok) * DIM + h * HD;
#pragma unroll
    for (int df = 0; df < 4; ++df) {
#pragma unroll
      for (int rp = 0; rp < 2; ++rp) {
        bf16x2 v2;
        v2[0] = (bf16_t)(o[df][qf][rp * 2]     * inv);
        v2[1] = (bf16_t)(o[df][qf][rp * 2 + 1] * inv);
        *(bf16x2*)(op + df * 16 + g * 4 + rp * 2) = v2;
      }
    }
  }
}

// ---------------- GEMM2: out = O @ W_proj + b (fp32 out) ----------------
__global__ __launch_bounds__(256) void k_gemm_proj(const bf16_t* __restrict__ Ob,
                                                   const bf16_t* __restrict__ WpT,
                                                   const float* __restrict__ bp,
                                                   float* __restrict__ out) {
  __shared__ alignas(16) bf16_t As[128 * 32];
  __shared__ alignas(16) bf16_t Bs[128 * 32];
  f32x4 acc[4][4];
  const int bm = blockIdx.y * 128, bn = blockIdx.x * 128;
  gemm_core(Ob, WpT, DIM, bm, bn, As, Bs, acc);

  const int lane = threadIdx.x & 63, w = threadIdx.x >> 6;
  const int wr = (w >> 1) * 64, wc = (w & 1) * 64;
  const int l15 = lane & 15, g = lane >> 4;
#pragma unroll
  for (int n = 0; n < 4; ++n) {
    int col = bn + wc + n * 16 + l15;
    float bias = bp[col];
#pragma unroll
    for (int m = 0; m < 4; ++m) {
      int rowb = bm + wr + m * 16 + g * 4;
#pragma unroll
      for (int r = 0; r < 4; ++r)
        out[(long)(rowb + r) * DIM + col] = acc[m][n][r] + bias;
    }
  }
}

// ---------------------------------------------------------------------------
extern "C" void kernel_launch(void* const* d_in, const int* in_sizes, int n_in,
                              void* d_out, int out_size, void* d_ws, size_t ws_size,
                              hipStream_t stream) {
  const float* x     = (const float*)d_in[0];
  const float* Wqkv  = (const float*)d_in[1];
  const float* bqkv  = (const float*)d_in[2];
  const float* Wproj = (const float*)d_in[3];
  const float* bproj = (const float*)d_in[4];
  float* out = (float*)d_out;

  char* ws = (char*)d_ws;
  bf16_t* xb  = (bf16_t*)(ws);                    // 8 MB
  bf16_t* WqT = (bf16_t*)(ws + (8l  << 20));      // 6 MB
  bf16_t* WpT = (bf16_t*)(ws + (14l << 20));      // 2 MB
  bf16_t* Qb  = (bf16_t*)(ws + (16l << 20));      // 8 MB
  bf16_t* Kb  = (bf16_t*)(ws + (24l << 20));      // 8 MB
  bf16_t* Vt  = (bf16_t*)(ws + (32l << 20));      // 8 MB
  bf16_t* Ob  = (bf16_t*)(ws);                    // aliases xb (x dead after gemm_qkv)

  k_cvt<<<2048, 256, 0, stream>>>(x, xb);                               // 4096*1024
  k_transpose_cvt<<<dim3(96, 32), 256, 0, stream>>>(Wqkv, WqT, 1024, 3072);
  k_transpose_cvt<<<dim3(32, 32), 256, 0, stream>>>(Wproj, WpT, 1024, 1024);
  k_gemm_qkv<<<dim3(24, 32), 256, 0, stream>>>(xb, WqT, bqkv, Qb, Kb, Vt);
  k_attn<<<512, 256, 0, stream>>>(Qb, Kb, Vt, Ob);
  k_gemm_proj<<<dim3(8, 32), 256, 0, stream>>>(Ob, WpT, bproj, out);
}